// Round 2
// baseline (736.993 us; speedup 1.0000x reference)
//
#include <hip/hip_runtime.h>
#include <hip/hip_bf16.h>

#define N_NODES 131072
#define BATCH 128
#define H 256

// ---------------------------------------------------------------------------
// Stage 1: scores[n] = tanh(X[n,:] @ W1 + b1) @ W2 + b2
// Block = 256 threads (4 waves), BM = 32 nodes. X tile staged in LDS.
// Wave w handles nodes [m0, m0+8); lane l handles cols [4l, 4l+4).
// W1 rows read as float4 (coalesced 1KB/wave, L2-resident: W1 = 256KB).
// ---------------------------------------------------------------------------
__global__ __launch_bounds__(256) void scores_kernel(
    const float* __restrict__ X, const float* __restrict__ W1,
    const float* __restrict__ b1, const float* __restrict__ W2,
    const float* __restrict__ b2, float* __restrict__ scores)
{
    __shared__ float Xs[32][H];
    const int tid = threadIdx.x;
    const long long block_base = (long long)blockIdx.x * 32;

    // stage X tile: 32*256 f32 = 2048 float4, 8 per thread, coalesced
    {
        const float4* src = reinterpret_cast<const float4*>(X + block_base * H);
        float4* dst = reinterpret_cast<float4*>(&Xs[0][0]);
        #pragma unroll
        for (int i = 0; i < 8; ++i) dst[tid + i * 256] = src[tid + i * 256];
    }
    __syncthreads();

    const int wave = tid >> 6;
    const int lane = tid & 63;
    const int m0 = wave * 8;

    float acc[8][4];
    {
        float4 bb = reinterpret_cast<const float4*>(b1)[lane];
        #pragma unroll
        for (int m = 0; m < 8; ++m) {
            acc[m][0] = bb.x; acc[m][1] = bb.y; acc[m][2] = bb.z; acc[m][3] = bb.w;
        }
    }

    const float4* W1v = reinterpret_cast<const float4*>(W1);
    #pragma unroll 2
    for (int k = 0; k < H; k += 4) {
        float wv[4][4];
        #pragma unroll
        for (int kk = 0; kk < 4; ++kk) {
            float4 t = W1v[(k + kk) * 64 + lane];
            wv[kk][0] = t.x; wv[kk][1] = t.y; wv[kk][2] = t.z; wv[kk][3] = t.w;
        }
        #pragma unroll
        for (int m = 0; m < 8; ++m) {
            float4 xv = *reinterpret_cast<const float4*>(&Xs[m0 + m][k]);
            float xa[4] = {xv.x, xv.y, xv.z, xv.w};
            #pragma unroll
            for (int kk = 0; kk < 4; ++kk) {
                #pragma unroll
                for (int c = 0; c < 4; ++c)
                    acc[m][c] = fmaf(xa[kk], wv[kk][c], acc[m][c]);
            }
        }
    }

    float w2a[4];
    {
        float4 t = reinterpret_cast<const float4*>(W2)[lane];
        w2a[0] = t.x; w2a[1] = t.y; w2a[2] = t.z; w2a[3] = t.w;
    }
    const float bias2 = b2[0];

    #pragma unroll
    for (int m = 0; m < 8; ++m) {
        float s = 0.f;
        #pragma unroll
        for (int c = 0; c < 4; ++c) s = fmaf(tanhf(acc[m][c]), w2a[c], s);
        #pragma unroll
        for (int off = 32; off; off >>= 1) s += __shfl_xor(s, off);
        if (lane == 0) scores[block_base + m0 + m] = s + bias2;
    }
}

// ---------------------------------------------------------------------------
// Stage 2: per-batch segment softmax over scores, weighted feature sum.
// Segment bounds faithful to the JAX code:
//   start[i] = offsets[i==0 ? 0 : i-1];  end[i] = (i<=B-3) ? offsets[i+2] : N
// One block (256 threads) per batch row. Two passes:
//   pass 1: online (max, sumexp) block reduction over segment scores
//   pass 2: wave w handles rows i == w (mod 4); lane l holds features 4l..4l+3
// NOTE: offsets arrive as int32 (harness converts all integer inputs).
// ---------------------------------------------------------------------------
__global__ __launch_bounds__(256) void aggregate_kernel(
    const float* __restrict__ X, const float* __restrict__ scores,
    const int* __restrict__ offsets, float* __restrict__ out)
{
    const int b = blockIdx.x;
    const int tid = threadIdx.x;
    const int lane = tid & 63;
    const int wave = tid >> 6;
    const int start = offsets[b == 0 ? 0 : b - 1];
    const int end = (b <= BATCH - 3) ? offsets[b + 2] : N_NODES;

    // ---- pass 1: online softmax stats ----
    float m = -1e30f, z = 0.f;
    for (int n = start + tid; n < end; n += 256) {
        float s = scores[n];
        float M = fmaxf(m, s);
        z = z * __expf(m - M) + __expf(s - M);
        m = M;
    }
    #pragma unroll
    for (int off = 32; off; off >>= 1) {
        float m2 = __shfl_xor(m, off);
        float z2 = __shfl_xor(z, off);
        float M = fmaxf(m, m2);
        z = z * __expf(m - M) + z2 * __expf(m2 - M);
        m = M;
    }
    __shared__ float sm[4], sz[4];
    if (lane == 0) { sm[wave] = m; sz[wave] = z; }
    __syncthreads();
    {
        float M = fmaxf(fmaxf(sm[0], sm[1]), fmaxf(sm[2], sm[3]));
        z = sz[0] * __expf(sm[0] - M) + sz[1] * __expf(sm[1] - M)
          + sz[2] * __expf(sm[2] - M) + sz[3] * __expf(sm[3] - M);
        m = M;
    }
    const float inv_z = 1.f / z;

    // ---- pass 2: weighted sum of features ----
    __shared__ float p[256];
    __shared__ float partial[4][H];
    float4 acc = {0.f, 0.f, 0.f, 0.f};
    for (int n0 = start; n0 < end; n0 += 256) {
        const int cnt = min(256, end - n0);
        __syncthreads();   // protect p from previous iteration's readers
        p[tid] = (tid < cnt) ? __expf(scores[n0 + tid] - m) : 0.f;
        __syncthreads();
        for (int i = wave; i < cnt; i += 4) {
            const float pi = p[i];
            float4 xv = reinterpret_cast<const float4*>(X + (long long)(n0 + i) * H)[lane];
            acc.x = fmaf(pi, xv.x, acc.x);
            acc.y = fmaf(pi, xv.y, acc.y);
            acc.z = fmaf(pi, xv.z, acc.z);
            acc.w = fmaf(pi, xv.w, acc.w);
        }
    }
    reinterpret_cast<float4*>(&partial[wave][0])[lane] = acc;
    __syncthreads();
    float r = partial[0][tid] + partial[1][tid] + partial[2][tid] + partial[3][tid];
    out[b * H + tid] = r * inv_z;
}

// ---------------------------------------------------------------------------
extern "C" void kernel_launch(void* const* d_in, const int* in_sizes, int n_in,
                              void* d_out, int out_size, void* d_ws, size_t ws_size,
                              hipStream_t stream)
{
    const float* X     = (const float*)d_in[0];
    const int* offs    = (const int*)d_in[1];   // int64 in ref -> int32 on device
    const float* W1    = (const float*)d_in[2];
    const float* b1    = (const float*)d_in[3];
    const float* W2    = (const float*)d_in[4];
    const float* b2    = (const float*)d_in[5];
    float* out         = (float*)d_out;
    float* scores      = (float*)d_ws;   // N_NODES floats = 512 KiB scratch

    scores_kernel<<<N_NODES / 32, 256, 0, stream>>>(X, W1, b1, W2, b2, scores);
    aggregate_kernel<<<BATCH, 256, 0, stream>>>(X, scores, offs, out);
}

// Round 3
// 305.370 us; speedup vs baseline: 2.4134x; 2.4134x over previous
//
#include <hip/hip_runtime.h>
#include <hip/hip_bf16.h>

#define N_NODES 131072
#define BATCH 128
#define H 256
#define SPLIT 16   // chunks per segment; grid = BATCH*SPLIT = 2048 blocks

// ---------------------------------------------------------------------------
// Stage 1: scores[n] = tanh(X[n,:] @ W1 + b1) @ W2 + b2   (unchanged)
// ---------------------------------------------------------------------------
__global__ __launch_bounds__(256) void scores_kernel(
    const float* __restrict__ X, const float* __restrict__ W1,
    const float* __restrict__ b1, const float* __restrict__ W2,
    const float* __restrict__ b2, float* __restrict__ scores)
{
    __shared__ float Xs[32][H];
    const int tid = threadIdx.x;
    const long long block_base = (long long)blockIdx.x * 32;

    {
        const float4* src = reinterpret_cast<const float4*>(X + block_base * H);
        float4* dst = reinterpret_cast<float4*>(&Xs[0][0]);
        #pragma unroll
        for (int i = 0; i < 8; ++i) dst[tid + i * 256] = src[tid + i * 256];
    }
    __syncthreads();

    const int wave = tid >> 6;
    const int lane = tid & 63;
    const int m0 = wave * 8;

    float acc[8][4];
    {
        float4 bb = reinterpret_cast<const float4*>(b1)[lane];
        #pragma unroll
        for (int m = 0; m < 8; ++m) {
            acc[m][0] = bb.x; acc[m][1] = bb.y; acc[m][2] = bb.z; acc[m][3] = bb.w;
        }
    }

    const float4* W1v = reinterpret_cast<const float4*>(W1);
    #pragma unroll 2
    for (int k = 0; k < H; k += 4) {
        float wv[4][4];
        #pragma unroll
        for (int kk = 0; kk < 4; ++kk) {
            float4 t = W1v[(k + kk) * 64 + lane];
            wv[kk][0] = t.x; wv[kk][1] = t.y; wv[kk][2] = t.z; wv[kk][3] = t.w;
        }
        #pragma unroll
        for (int m = 0; m < 8; ++m) {
            float4 xv = *reinterpret_cast<const float4*>(&Xs[m0 + m][k]);
            float xa[4] = {xv.x, xv.y, xv.z, xv.w};
            #pragma unroll
            for (int kk = 0; kk < 4; ++kk) {
                #pragma unroll
                for (int c = 0; c < 4; ++c)
                    acc[m][c] = fmaf(xa[kk], wv[kk][c], acc[m][c]);
            }
        }
    }

    float w2a[4];
    {
        float4 t = reinterpret_cast<const float4*>(W2)[lane];
        w2a[0] = t.x; w2a[1] = t.y; w2a[2] = t.z; w2a[3] = t.w;
    }
    const float bias2 = b2[0];

    #pragma unroll
    for (int m = 0; m < 8; ++m) {
        float s = 0.f;
        #pragma unroll
        for (int c = 0; c < 4; ++c) s = fmaf(tanhf(acc[m][c]), w2a[c], s);
        #pragma unroll
        for (int off = 32; off; off >>= 1) s += __shfl_xor(s, off);
        if (lane == 0) scores[block_base + m0 + m] = s + bias2;
    }
}

// ---------------------------------------------------------------------------
// Stage 2a: per-(batch, chunk) softmax partials.
// Segment [start,end) split into SPLIT fixed chunks (deterministic).
// Each block: local max m, local z = sum exp(s-m), local acc = sum exp(s-m)*x.
// ---------------------------------------------------------------------------
__global__ __launch_bounds__(256) void partial_kernel(
    const float* __restrict__ X, const float* __restrict__ scores,
    const int* __restrict__ offsets,
    float* __restrict__ pm, float* __restrict__ pz, float* __restrict__ pacc)
{
    const int b = blockIdx.x / SPLIT;
    const int s = blockIdx.x % SPLIT;
    const int tid = threadIdx.x;
    const int lane = tid & 63;
    const int wave = tid >> 6;

    const int start = offsets[b == 0 ? 0 : b - 1];
    const int end = (b <= BATCH - 3) ? offsets[b + 2] : N_NODES;
    const int L = end - start;
    const int chunk = (L + SPLIT - 1) / SPLIT;
    const int cs = start + s * chunk;
    const int ce = min(cs + chunk, end);

    // ---- pass 1: local (m, z) over chunk scores ----
    float m = -1e30f, z = 0.f;
    for (int n = cs + tid; n < ce; n += 256) {
        float sc = scores[n];
        float M = fmaxf(m, sc);
        z = z * __expf(m - M) + __expf(sc - M);
        m = M;
    }
    #pragma unroll
    for (int off = 32; off; off >>= 1) {
        float m2 = __shfl_xor(m, off);
        float z2 = __shfl_xor(z, off);
        float M = fmaxf(m, m2);
        z = z * __expf(m - M) + z2 * __expf(m2 - M);
        m = M;
    }
    __shared__ float sm[4], sz[4];
    if (lane == 0) { sm[wave] = m; sz[wave] = z; }
    __syncthreads();
    {
        float M = fmaxf(fmaxf(sm[0], sm[1]), fmaxf(sm[2], sm[3]));
        z = sz[0] * __expf(sm[0] - M) + sz[1] * __expf(sm[1] - M)
          + sz[2] * __expf(sm[2] - M) + sz[3] * __expf(sm[3] - M);
        m = M;
    }

    // ---- pass 2: acc = sum exp(s - m) * x over chunk ----
    __shared__ float p[256];
    __shared__ float partial[4][H];
    float4 acc = {0.f, 0.f, 0.f, 0.f};
    for (int n0 = cs; n0 < ce; n0 += 256) {
        const int cnt = min(256, ce - n0);
        __syncthreads();
        p[tid] = (tid < cnt) ? __expf(scores[n0 + tid] - m) : 0.f;
        __syncthreads();
        for (int i = wave; i < cnt; i += 4) {
            const float pi = p[i];
            float4 xv = reinterpret_cast<const float4*>(X + (long long)(n0 + i) * H)[lane];
            acc.x = fmaf(pi, xv.x, acc.x);
            acc.y = fmaf(pi, xv.y, acc.y);
            acc.z = fmaf(pi, xv.z, acc.z);
            acc.w = fmaf(pi, xv.w, acc.w);
        }
    }
    reinterpret_cast<float4*>(&partial[wave][0])[lane] = acc;
    __syncthreads();
    float r = partial[0][tid] + partial[1][tid] + partial[2][tid] + partial[3][tid];

    const int pidx = b * SPLIT + s;
    pacc[(long long)pidx * H + tid] = r;
    if (tid == 0) { pm[pidx] = m; pz[pidx] = z; }
}

// ---------------------------------------------------------------------------
// Stage 2b: combine SPLIT chunks per batch row with max-rescaling.
// Grid = BATCH blocks x 256 threads (thread = feature column).
// ---------------------------------------------------------------------------
__global__ __launch_bounds__(256) void reduce_kernel(
    const float* __restrict__ pm, const float* __restrict__ pz,
    const float* __restrict__ pacc, float* __restrict__ out)
{
    const int b = blockIdx.x;
    const int tid = threadIdx.x;
    const int base = b * SPLIT;

    float M = -1e30f;
    #pragma unroll
    for (int s = 0; s < SPLIT; ++s) M = fmaxf(M, pm[base + s]);

    float z = 0.f, r = 0.f;
    #pragma unroll
    for (int s = 0; s < SPLIT; ++s) {
        const float w = __expf(pm[base + s] - M);
        z = fmaf(pz[base + s], w, z);
        r = fmaf(pacc[(long long)(base + s) * H + tid], w, r);
    }
    out[b * H + tid] = r / z;
}

// ---------------------------------------------------------------------------
extern "C" void kernel_launch(void* const* d_in, const int* in_sizes, int n_in,
                              void* d_out, int out_size, void* d_ws, size_t ws_size,
                              hipStream_t stream)
{
    const float* X     = (const float*)d_in[0];
    const int* offs    = (const int*)d_in[1];   // int64 in ref -> int32 on device
    const float* W1    = (const float*)d_in[2];
    const float* b1    = (const float*)d_in[3];
    const float* W2    = (const float*)d_in[4];
    const float* b2    = (const float*)d_in[5];
    float* out         = (float*)d_out;

    // workspace layout (floats):
    //   [0, N)                 scores
    //   [N, N+BS)              pm      (BS = BATCH*SPLIT)
    //   [N+BS, N+2BS)          pz
    //   [N+2BS, N+2BS+BS*H)    pacc
    float* scores = (float*)d_ws;
    float* pm     = scores + N_NODES;
    float* pz     = pm + BATCH * SPLIT;
    float* pacc   = pz + BATCH * SPLIT;

    scores_kernel<<<N_NODES / 32, 256, 0, stream>>>(X, W1, b1, W2, b2, scores);
    partial_kernel<<<BATCH * SPLIT, 256, 0, stream>>>(X, scores, offs, pm, pz, pacc);
    reduce_kernel<<<BATCH, 256, 0, stream>>>(pm, pz, pacc, out);
}

// Round 4
// 117.583 us; speedup vs baseline: 6.2678x; 2.5970x over previous
//
#include <hip/hip_runtime.h>
#include <hip/hip_bf16.h>

#define N_NODES 131072
#define BATCH 128
#define H 256
#define SPLIT 16   // chunks per segment; grid = BATCH*SPLIT = 2048 blocks

typedef _Float16 half8 __attribute__((ext_vector_type(8)));
typedef float floatx4 __attribute__((ext_vector_type(4)));

// ---------------------------------------------------------------------------
// Pack W1 (f32 row-major KxN, K=H, N=H) into fragment-ordered f16 for
// mfma_f32_16x16x32_f16 B-operand.
// Chunk g = (ct*8 + ks)*64 + lane holds 8 f16:
//   W1[ks*32 + (lane>>4)*8 + j][ct*16 + (lane&15)], j=0..7
// 8192 chunks -> 32 blocks x 256 threads, one chunk per thread.
// ---------------------------------------------------------------------------
__global__ __launch_bounds__(256) void w1_pack_kernel(
    const float* __restrict__ W1, _Float16* __restrict__ W1p)
{
    const int g = blockIdx.x * 256 + threadIdx.x;   // [0, 8192)
    const int ct = g >> 9;
    const int ks = (g >> 6) & 7;
    const int l  = g & 63;
    const int k0 = ks * 32 + (l >> 4) * 8;
    const int col = ct * 16 + (l & 15);
    half8 h;
    #pragma unroll
    for (int j = 0; j < 8; ++j) h[j] = (_Float16)W1[(k0 + j) * H + col];
    reinterpret_cast<half8*>(W1p)[g] = h;
}

// ---------------------------------------------------------------------------
// Stage 1: scores[n] = tanh(X[n,:] @ W1 + b1) @ W2 + b2 via f16 MFMA.
// Block = 256 threads (4 waves), BM = 64 rows. X tile f32->f16 staged into
// XOR-swizzled LDS (byte ^= (row&7)<<4 -> 2-way-free ds_read_b128).
// Wave w owns output cols [w*64, w*64+64) as 4 col-tiles; 4x4 acc tiles.
// Epilogue: x = acc + b1; tanh(x) = 1 - 2/(exp(2x)+1) (overflow-safe);
// dot with W2 in-register, 16-lane shuffle reduce, cross-wave via LDS.
// ---------------------------------------------------------------------------
__global__ __launch_bounds__(256) void scores_mfma_kernel(
    const float* __restrict__ X, const _Float16* __restrict__ W1p,
    const float* __restrict__ b1, const float* __restrict__ W2,
    const float* __restrict__ b2, float* __restrict__ scores)
{
    __shared__ __align__(16) _Float16 Xs[64 * H];   // 32 KB, swizzled
    __shared__ float sp[4][64];

    const int tid = threadIdx.x;
    const int wave = tid >> 6;
    const int lane = tid & 63;
    const long long base = (long long)blockIdx.x * 64;

    // ---- stage X tile: 64 rows x 256 cols f32 -> f16 LDS (swizzled) ----
    {
        const float4* Xv = reinterpret_cast<const float4*>(X + base * H);
        #pragma unroll
        for (int i = 0; i < 8; ++i) {
            const int c = tid + i * 256;        // chunk id, 2048 chunks
            const int row = c >> 5;             // 32 chunks per row
            const int col8 = c & 31;
            float4 a = Xv[row * 64 + col8 * 2];
            float4 bq = Xv[row * 64 + col8 * 2 + 1];
            half8 h;
            h[0] = (_Float16)a.x;  h[1] = (_Float16)a.y;
            h[2] = (_Float16)a.z;  h[3] = (_Float16)a.w;
            h[4] = (_Float16)bq.x; h[5] = (_Float16)bq.y;
            h[6] = (_Float16)bq.z; h[7] = (_Float16)bq.w;
            int byte = row * 512 + col8 * 16;
            byte ^= (row & 7) << 4;
            *reinterpret_cast<half8*>(reinterpret_cast<char*>(Xs) + byte) = h;
        }
    }
    __syncthreads();

    floatx4 acc[4][4];
    #pragma unroll
    for (int rt = 0; rt < 4; ++rt)
        #pragma unroll
        for (int ctl = 0; ctl < 4; ++ctl)
            acc[rt][ctl] = (floatx4){0.f, 0.f, 0.f, 0.f};

    const half8* Bv = reinterpret_cast<const half8*>(W1p);

    #pragma unroll
    for (int ks = 0; ks < 8; ++ks) {
        half8 af[4];
        #pragma unroll
        for (int rt = 0; rt < 4; ++rt) {
            const int row = rt * 16 + (lane & 15);
            int byte = row * 512 + ks * 64 + (lane >> 4) * 16;
            byte ^= (row & 7) << 4;
            af[rt] = *reinterpret_cast<const half8*>(
                reinterpret_cast<const char*>(Xs) + byte);
        }
        half8 bf[4];
        #pragma unroll
        for (int ctl = 0; ctl < 4; ++ctl) {
            const int ct = wave * 4 + ctl;
            bf[ctl] = Bv[(ct * 8 + ks) * 64 + lane];
        }
        #pragma unroll
        for (int rt = 0; rt < 4; ++rt)
            #pragma unroll
            for (int ctl = 0; ctl < 4; ++ctl)
                acc[rt][ctl] = __builtin_amdgcn_mfma_f32_16x16x32_f16(
                    af[rt], bf[ctl], acc[rt][ctl], 0, 0, 0);
    }

    // ---- epilogue: tanh + W2 dot ----
    float w2v[4], b1v[4];
    #pragma unroll
    for (int ctl = 0; ctl < 4; ++ctl) {
        const int col = wave * 64 + ctl * 16 + (lane & 15);
        w2v[ctl] = W2[col];
        b1v[ctl] = b1[col];
    }

    float sc[4][4];
    #pragma unroll
    for (int rt = 0; rt < 4; ++rt) {
        #pragma unroll
        for (int reg = 0; reg < 4; ++reg) {
            float s = 0.f;
            #pragma unroll
            for (int ctl = 0; ctl < 4; ++ctl) {
                const float x = acc[rt][ctl][reg] + b1v[ctl];
                const float t = 1.f - 2.f / (__expf(2.f * x) + 1.f);
                s = fmaf(t, w2v[ctl], s);
            }
            sc[rt][reg] = s;
        }
    }
    // reduce across the 16 lanes holding different cols of the same rows
    #pragma unroll
    for (int off = 1; off < 16; off <<= 1)
        #pragma unroll
        for (int rt = 0; rt < 4; ++rt)
            #pragma unroll
            for (int reg = 0; reg < 4; ++reg)
                sc[rt][reg] += __shfl_xor(sc[rt][reg], off);

    if ((lane & 15) == 0) {
        #pragma unroll
        for (int rt = 0; rt < 4; ++rt)
            #pragma unroll
            for (int reg = 0; reg < 4; ++reg)
                sp[wave][rt * 16 + (lane >> 4) * 4 + reg] = sc[rt][reg];
    }
    __syncthreads();
    if (tid < 64)
        scores[base + tid] = sp[0][tid] + sp[1][tid] + sp[2][tid] + sp[3][tid] + b2[0];
}

// ---------------------------------------------------------------------------
// Stage 2a: per-(batch, chunk) softmax partials.  (unchanged from round 3)
// ---------------------------------------------------------------------------
__global__ __launch_bounds__(256) void partial_kernel(
    const float* __restrict__ X, const float* __restrict__ scores,
    const int* __restrict__ offsets,
    float* __restrict__ pm, float* __restrict__ pz, float* __restrict__ pacc)
{
    const int b = blockIdx.x / SPLIT;
    const int s = blockIdx.x % SPLIT;
    const int tid = threadIdx.x;
    const int lane = tid & 63;
    const int wave = tid >> 6;

    const int start = offsets[b == 0 ? 0 : b - 1];
    const int end = (b <= BATCH - 3) ? offsets[b + 2] : N_NODES;
    const int L = end - start;
    const int chunk = (L + SPLIT - 1) / SPLIT;
    const int cs = start + s * chunk;
    const int ce = min(cs + chunk, end);

    float m = -1e30f, z = 0.f;
    for (int n = cs + tid; n < ce; n += 256) {
        float sco = scores[n];
        float M = fmaxf(m, sco);
        z = z * __expf(m - M) + __expf(sco - M);
        m = M;
    }
    #pragma unroll
    for (int off = 32; off; off >>= 1) {
        float m2 = __shfl_xor(m, off);
        float z2 = __shfl_xor(z, off);
        float M = fmaxf(m, m2);
        z = z * __expf(m - M) + z2 * __expf(m2 - M);
        m = M;
    }
    __shared__ float sm[4], sz[4];
    if (lane == 0) { sm[wave] = m; sz[wave] = z; }
    __syncthreads();
    {
        float M = fmaxf(fmaxf(sm[0], sm[1]), fmaxf(sm[2], sm[3]));
        z = sz[0] * __expf(sm[0] - M) + sz[1] * __expf(sm[1] - M)
          + sz[2] * __expf(sm[2] - M) + sz[3] * __expf(sm[3] - M);
        m = M;
    }

    __shared__ float p[256];
    __shared__ float partial[4][H];
    float4 acc = {0.f, 0.f, 0.f, 0.f};
    for (int n0 = cs; n0 < ce; n0 += 256) {
        const int cnt = min(256, ce - n0);
        __syncthreads();
        p[tid] = (tid < cnt) ? __expf(scores[n0 + tid] - m) : 0.f;
        __syncthreads();
        for (int i = wave; i < cnt; i += 4) {
            const float pi = p[i];
            float4 xv = reinterpret_cast<const float4*>(X + (long long)(n0 + i) * H)[lane];
            acc.x = fmaf(pi, xv.x, acc.x);
            acc.y = fmaf(pi, xv.y, acc.y);
            acc.z = fmaf(pi, xv.z, acc.z);
            acc.w = fmaf(pi, xv.w, acc.w);
        }
    }
    reinterpret_cast<float4*>(&partial[wave][0])[lane] = acc;
    __syncthreads();
    float r = partial[0][tid] + partial[1][tid] + partial[2][tid] + partial[3][tid];

    const int pidx = b * SPLIT + s;
    pacc[(long long)pidx * H + tid] = r;
    if (tid == 0) { pm[pidx] = m; pz[pidx] = z; }
}

// ---------------------------------------------------------------------------
// Stage 2b: combine SPLIT chunks per batch row with max-rescaling.
// ---------------------------------------------------------------------------
__global__ __launch_bounds__(256) void reduce_kernel(
    const float* __restrict__ pm, const float* __restrict__ pz,
    const float* __restrict__ pacc, float* __restrict__ out)
{
    const int b = blockIdx.x;
    const int tid = threadIdx.x;
    const int base = b * SPLIT;

    float M = -1e30f;
    #pragma unroll
    for (int s = 0; s < SPLIT; ++s) M = fmaxf(M, pm[base + s]);

    float z = 0.f, r = 0.f;
    #pragma unroll
    for (int s = 0; s < SPLIT; ++s) {
        const float w = __expf(pm[base + s] - M);
        z = fmaf(pz[base + s], w, z);
        r = fmaf(pacc[(long long)(base + s) * H + tid], w, r);
    }
    out[b * H + tid] = r / z;
}

// ---------------------------------------------------------------------------
extern "C" void kernel_launch(void* const* d_in, const int* in_sizes, int n_in,
                              void* d_out, int out_size, void* d_ws, size_t ws_size,
                              hipStream_t stream)
{
    const float* X     = (const float*)d_in[0];
    const int* offs    = (const int*)d_in[1];   // int64 in ref -> int32 on device
    const float* W1    = (const float*)d_in[2];
    const float* b1    = (const float*)d_in[3];
    const float* W2    = (const float*)d_in[4];
    const float* b2    = (const float*)d_in[5];
    float* out         = (float*)d_out;

    // workspace layout (floats):
    //   [0, N)                      scores
    //   [N, N+BS)                   pm      (BS = BATCH*SPLIT = 2048)
    //   [N+BS, N+2BS)               pz
    //   [N+2BS, N+2BS+BS*H)         pacc
    //   [.., +32768)                W1p (65536 f16 = 32768 float slots)
    float* scores   = (float*)d_ws;
    float* pm       = scores + N_NODES;
    float* pz       = pm + BATCH * SPLIT;
    float* pacc     = pz + BATCH * SPLIT;
    _Float16* W1p   = (_Float16*)(pacc + (size_t)BATCH * SPLIT * H);

    w1_pack_kernel<<<32, 256, 0, stream>>>(W1, W1p);
    scores_mfma_kernel<<<N_NODES / 64, 256, 0, stream>>>(X, W1p, b1, W2, b2, scores);
    partial_kernel<<<BATCH * SPLIT, 256, 0, stream>>>(X, scores, offs, pm, pz, pacc);
    reduce_kernel<<<BATCH, 256, 0, stream>>>(pm, pz, pacc, out);
}

// Round 5
// 92.489 us; speedup vs baseline: 7.9684x; 1.2713x over previous
//
#include <hip/hip_runtime.h>
#include <hip/hip_bf16.h>

#define N_NODES 131072
#define BATCH 128
#define H 256
#define SPLIT 16   // chunks per GAP; grid = 128 gaps * SPLIT = 2048 blocks

typedef _Float16 half8 __attribute__((ext_vector_type(8)));
typedef float floatx4 __attribute__((ext_vector_type(4)));

// ---------------------------------------------------------------------------
// Pack W1 (f32 row-major KxN, K=H, N=H) into fragment-ordered f16 for
// mfma_f32_16x16x32_f16 B-operand. (unchanged)
// ---------------------------------------------------------------------------
__global__ __launch_bounds__(256) void w1_pack_kernel(
    const float* __restrict__ W1, _Float16* __restrict__ W1p)
{
    const int g = blockIdx.x * 256 + threadIdx.x;   // [0, 8192)
    const int ct = g >> 9;
    const int ks = (g >> 6) & 7;
    const int l  = g & 63;
    const int k0 = ks * 32 + (l >> 4) * 8;
    const int col = ct * 16 + (l & 15);
    half8 h;
    #pragma unroll
    for (int j = 0; j < 8; ++j) h[j] = (_Float16)W1[(k0 + j) * H + col];
    reinterpret_cast<half8*>(W1p)[g] = h;
}

// ---------------------------------------------------------------------------
// Stage 1: scores = tanh(X @ W1 + b1) @ W2 + b2 via f16 MFMA. (unchanged)
// ---------------------------------------------------------------------------
__global__ __launch_bounds__(256) void scores_mfma_kernel(
    const float* __restrict__ X, const _Float16* __restrict__ W1p,
    const float* __restrict__ b1, const float* __restrict__ W2,
    const float* __restrict__ b2, float* __restrict__ scores)
{
    __shared__ __align__(16) _Float16 Xs[64 * H];   // 32 KB, swizzled
    __shared__ float sp[4][64];

    const int tid = threadIdx.x;
    const int wave = tid >> 6;
    const int lane = tid & 63;
    const long long base = (long long)blockIdx.x * 64;

    {
        const float4* Xv = reinterpret_cast<const float4*>(X + base * H);
        #pragma unroll
        for (int i = 0; i < 8; ++i) {
            const int c = tid + i * 256;
            const int row = c >> 5;
            const int col8 = c & 31;
            float4 a = Xv[row * 64 + col8 * 2];
            float4 bq = Xv[row * 64 + col8 * 2 + 1];
            half8 h;
            h[0] = (_Float16)a.x;  h[1] = (_Float16)a.y;
            h[2] = (_Float16)a.z;  h[3] = (_Float16)a.w;
            h[4] = (_Float16)bq.x; h[5] = (_Float16)bq.y;
            h[6] = (_Float16)bq.z; h[7] = (_Float16)bq.w;
            int byte = row * 512 + col8 * 16;
            byte ^= (row & 7) << 4;
            *reinterpret_cast<half8*>(reinterpret_cast<char*>(Xs) + byte) = h;
        }
    }
    __syncthreads();

    floatx4 acc[4][4];
    #pragma unroll
    for (int rt = 0; rt < 4; ++rt)
        #pragma unroll
        for (int ctl = 0; ctl < 4; ++ctl)
            acc[rt][ctl] = (floatx4){0.f, 0.f, 0.f, 0.f};

    const half8* Bv = reinterpret_cast<const half8*>(W1p);

    #pragma unroll
    for (int ks = 0; ks < 8; ++ks) {
        half8 af[4];
        #pragma unroll
        for (int rt = 0; rt < 4; ++rt) {
            const int row = rt * 16 + (lane & 15);
            int byte = row * 512 + ks * 64 + (lane >> 4) * 16;
            byte ^= (row & 7) << 4;
            af[rt] = *reinterpret_cast<const half8*>(
                reinterpret_cast<const char*>(Xs) + byte);
        }
        half8 bf[4];
        #pragma unroll
        for (int ctl = 0; ctl < 4; ++ctl) {
            const int ct = wave * 4 + ctl;
            bf[ctl] = Bv[(ct * 8 + ks) * 64 + lane];
        }
        #pragma unroll
        for (int rt = 0; rt < 4; ++rt)
            #pragma unroll
            for (int ctl = 0; ctl < 4; ++ctl)
                acc[rt][ctl] = __builtin_amdgcn_mfma_f32_16x16x32_f16(
                    af[rt], bf[ctl], acc[rt][ctl], 0, 0, 0);
    }

    float w2v[4], b1v[4];
    #pragma unroll
    for (int ctl = 0; ctl < 4; ++ctl) {
        const int col = wave * 64 + ctl * 16 + (lane & 15);
        w2v[ctl] = W2[col];
        b1v[ctl] = b1[col];
    }

    float sc[4][4];
    #pragma unroll
    for (int rt = 0; rt < 4; ++rt) {
        #pragma unroll
        for (int reg = 0; reg < 4; ++reg) {
            float s = 0.f;
            #pragma unroll
            for (int ctl = 0; ctl < 4; ++ctl) {
                const float x = acc[rt][ctl][reg] + b1v[ctl];
                const float t = 1.f - 2.f / (__expf(2.f * x) + 1.f);
                s = fmaf(t, w2v[ctl], s);
            }
            sc[rt][reg] = s;
        }
    }
    #pragma unroll
    for (int off = 1; off < 16; off <<= 1)
        #pragma unroll
        for (int rt = 0; rt < 4; ++rt)
            #pragma unroll
            for (int reg = 0; reg < 4; ++reg)
                sc[rt][reg] += __shfl_xor(sc[rt][reg], off);

    if ((lane & 15) == 0) {
        #pragma unroll
        for (int rt = 0; rt < 4; ++rt)
            #pragma unroll
            for (int reg = 0; reg < 4; ++reg)
                sp[wave][rt * 16 + (lane >> 4) * 4 + reg] = sc[rt][reg];
    }
    __syncthreads();
    if (tid < 64)
        scores[base + tid] = sp[0][tid] + sp[1][tid] + sp[2][tid] + sp[3][tid] + b2[0];
}

// ---------------------------------------------------------------------------
// Stage 2a: per-(GAP, chunk) softmax partials. gap g = [offsets[g],
// offsets[g+1]) for g<127, [offsets[127], N) for g=127. Each node is read
// exactly ONCE here (vs 3x with per-segment chunks) — segments are unions
// of <=3 gaps and get recombined in the reduce with max-rescaling.
// ---------------------------------------------------------------------------
__global__ __launch_bounds__(256) void partial_kernel(
    const float* __restrict__ X, const float* __restrict__ scores,
    const int* __restrict__ offsets,
    float* __restrict__ pm, float* __restrict__ pz, float* __restrict__ pacc)
{
    const int gp = blockIdx.x >> 4;      // gap id, 0..127
    const int s = blockIdx.x & 15;       // chunk within gap
    const int tid = threadIdx.x;
    const int lane = tid & 63;
    const int wave = tid >> 6;

    const int gs = offsets[gp];
    const int ge = (gp == BATCH - 1) ? N_NODES : offsets[gp + 1];
    const int L = ge - gs;
    const int chunk = (L + SPLIT - 1) / SPLIT;
    const int cs = gs + s * chunk;
    const int ce = min(cs + chunk, ge);

    // ---- pass 1: local (m, z) over chunk scores ----
    float m = -1e30f, z = 0.f;
    for (int n = cs + tid; n < ce; n += 256) {
        float sco = scores[n];
        float M = fmaxf(m, sco);
        z = z * __expf(m - M) + __expf(sco - M);
        m = M;
    }
    #pragma unroll
    for (int off = 32; off; off >>= 1) {
        float m2 = __shfl_xor(m, off);
        float z2 = __shfl_xor(z, off);
        float M = fmaxf(m, m2);
        z = z * __expf(m - M) + z2 * __expf(m2 - M);
        m = M;
    }
    __shared__ float sm[4], sz[4];
    if (lane == 0) { sm[wave] = m; sz[wave] = z; }
    __syncthreads();
    {
        float M = fmaxf(fmaxf(sm[0], sm[1]), fmaxf(sm[2], sm[3]));
        z = sz[0] * __expf(sm[0] - M) + sz[1] * __expf(sm[1] - M)
          + sz[2] * __expf(sm[2] - M) + sz[3] * __expf(sm[3] - M);
        m = M;
    }

    // ---- pass 2: acc = sum exp(s - m) * x over chunk ----
    __shared__ float p[256];
    __shared__ float partial[4][H];
    float4 acc = {0.f, 0.f, 0.f, 0.f};
    for (int n0 = cs; n0 < ce; n0 += 256) {
        const int cnt = min(256, ce - n0);
        __syncthreads();
        p[tid] = (tid < cnt) ? __expf(scores[n0 + tid] - m) : 0.f;
        __syncthreads();
        for (int i = wave; i < cnt; i += 4) {
            const float pi = p[i];
            float4 xv = reinterpret_cast<const float4*>(X + (long long)(n0 + i) * H)[lane];
            acc.x = fmaf(pi, xv.x, acc.x);
            acc.y = fmaf(pi, xv.y, acc.y);
            acc.z = fmaf(pi, xv.z, acc.z);
            acc.w = fmaf(pi, xv.w, acc.w);
        }
    }
    reinterpret_cast<float4*>(&partial[wave][0])[lane] = acc;
    __syncthreads();
    float r = partial[0][tid] + partial[1][tid] + partial[2][tid] + partial[3][tid];

    const int pidx = gp * SPLIT + s;
    pacc[(long long)pidx * H + tid] = r;
    if (tid == 0) { pm[pidx] = m; pz[pidx] = z; }
}

// ---------------------------------------------------------------------------
// Stage 2b: segment b = union of gaps [max(b-1,0), min(b+1,127)].
// Combine those gaps' chunk partials with max-rescaling.
// ---------------------------------------------------------------------------
__global__ __launch_bounds__(256) void reduce_kernel(
    const float* __restrict__ pm, const float* __restrict__ pz,
    const float* __restrict__ pacc, float* __restrict__ out)
{
    const int b = blockIdx.x;
    const int tid = threadIdx.x;
    const int g0 = (b == 0) ? 0 : b - 1;
    const int g1 = (b >= BATCH - 1) ? BATCH - 1 : b + 1;
    const int s0 = g0 * SPLIT;
    const int s1 = (g1 + 1) * SPLIT;   // exclusive

    float M = -1e30f;
    for (int s = s0; s < s1; ++s) M = fmaxf(M, pm[s]);

    float z = 0.f, r = 0.f;
    for (int s = s0; s < s1; ++s) {
        const float w = __expf(pm[s] - M);
        z = fmaf(pz[s], w, z);
        r = fmaf(pacc[(long long)s * H + tid], w, r);
    }
    out[b * H + tid] = r / z;
}

// ---------------------------------------------------------------------------
extern "C" void kernel_launch(void* const* d_in, const int* in_sizes, int n_in,
                              void* d_out, int out_size, void* d_ws, size_t ws_size,
                              hipStream_t stream)
{
    const float* X     = (const float*)d_in[0];
    const int* offs    = (const int*)d_in[1];   // int64 in ref -> int32 on device
    const float* W1    = (const float*)d_in[2];
    const float* b1    = (const float*)d_in[3];
    const float* W2    = (const float*)d_in[4];
    const float* b2    = (const float*)d_in[5];
    float* out         = (float*)d_out;

    // workspace layout (floats):
    //   [0, N)                      scores
    //   [N, N+BS)                   pm      (BS = 128 gaps * SPLIT = 2048)
    //   [N+BS, N+2BS)               pz
    //   [N+2BS, N+2BS+BS*H)         pacc
    //   [.., +32768)                W1p (65536 f16)
    float* scores   = (float*)d_ws;
    float* pm       = scores + N_NODES;
    float* pz       = pm + BATCH * SPLIT;
    float* pacc     = pz + BATCH * SPLIT;
    _Float16* W1p   = (_Float16*)(pacc + (size_t)BATCH * SPLIT * H);

    w1_pack_kernel<<<32, 256, 0, stream>>>(W1, W1p);
    scores_mfma_kernel<<<N_NODES / 64, 256, 0, stream>>>(X, W1p, b1, W2, b2, scores);
    partial_kernel<<<BATCH * SPLIT, 256, 0, stream>>>(X, scores, offs, pm, pz, pacc);
    reduce_kernel<<<BATCH, 256, 0, stream>>>(pm, pz, pacc, out);
}